// Round 9
// baseline (387.501 us; speedup 1.0000x reference)
//
#include <hip/hip_runtime.h>
#include <hip/hip_bf16.h>

#define N_NODES  50000
#define N_EDGES  50000
#define N_INC    400000
#define N_GRAPHS 1024
#define M_PAD    50048          // 391 * 128
#define SEG_CAP  50176          // 49 * 1024 (scan padding)

typedef _Float16 f16x8 __attribute__((ext_vector_type(8)));
typedef _Float16 h16x2 __attribute__((ext_vector_type(2)));
typedef float    f32x4 __attribute__((ext_vector_type(4)));

__device__ __forceinline__ unsigned short f2h(float f) {
    _Float16 h = (_Float16)f;                      // v_cvt_f16_f32 (RTE)
    return __builtin_bit_cast(unsigned short, h);
}
__device__ __forceinline__ float h2f(unsigned short u) {
    return (float)__builtin_bit_cast(_Float16, u);
}
__device__ __forceinline__ unsigned int packh(float a, float b) {
    return (unsigned int)f2h(a) | ((unsigned int)f2h(b) << 16);
}
__device__ __forceinline__ void load_lds16(const unsigned short* g, unsigned short* l) {
    __builtin_amdgcn_global_load_lds((const __attribute__((address_space(1))) void*)g,
                                     (__attribute__((address_space(3))) void*)l, 16, 0, 0);
}

// ---- normhist: incidence histogram only (padded counters, atomic returns = rank) --
#define NB_INC  1563
__global__ __launch_bounds__(256) void normhist_kernel(const int* __restrict__ hei,
                                                       int* __restrict__ nidx, int* __restrict__ eidx,
                                                       unsigned short* __restrict__ rn,
                                                       unsigned short* __restrict__ re,
                                                       int* __restrict__ ndeg_p, int* __restrict__ edeg_p) {
    __shared__ int s32;
    int t = threadIdx.x;
    if (t == 0) s32 = 0;
    __syncthreads();
    int probe = hei[4 * t + 1] | hei[4 * t + 3];   // int64 layout => odd words zero
    if (probe) s32 = 1;
    __syncthreads();
    int is32 = s32;
    int i = blockIdx.x * 256 + t;
    if (i < N_INC) {
        int n, e;
        if (is32) { n = hei[i];     e = hei[N_INC + i]; }
        else      { n = hei[2 * i]; e = hei[2 * N_INC + 2 * i]; }
        nidx[i] = n; eidx[i] = e;
        rn[i] = (unsigned short)atomicAdd(&ndeg_p[n << 4], 1);
        re[i] = (unsigned short)atomicAdd(&edeg_p[e << 4], 1);
    }
}

// ---- scan_up over padded degree arrays + goff via binary search on sorted batch
__global__ __launch_bounds__(256) void scan_up_f(const int* __restrict__ edeg_p,
                                                 const int* __restrict__ ndeg_p,
                                                 const int* __restrict__ hei,
                                                 const int* __restrict__ braw,
                                                 int* __restrict__ eoff, int* __restrict__ noff,
                                                 int* __restrict__ goff,
                                                 int* __restrict__ partials) {
    int b = blockIdx.x, t = threadIdx.x;
    if (b >= 98) {
        __shared__ int s32;
        if (t == 0) s32 = 0;
        __syncthreads();
        int probe = hei[4 * t + 1] | hei[4 * t + 3];
        if (probe) s32 = 1;
        __syncthreads();
        int is32 = s32;
        int g = (b - 98) * 256 + t;
        int lo = 0, hi = N_NODES;
        while (lo < hi) {
            int mid = (lo + hi) >> 1;
            int v = is32 ? braw[mid] : braw[2 * mid];
            if (v < g) lo = mid + 1; else hi = mid;
        }
        goff[g] = lo;
        if (g == 1023) goff[1024] = N_NODES;
        return;
    }
    __shared__ int lds[256];
    const int* in; int* outp; int lb;
    if (b < 49) { in = edeg_p; outp = eoff; lb = b; }
    else        { in = ndeg_p; outp = noff; lb = b - 49; }
    int base = lb * 1024 + t * 4;
    int4 v;
    v.x = in[(size_t)(base + 0) << 4];
    v.y = in[(size_t)(base + 1) << 4];
    v.z = in[(size_t)(base + 2) << 4];
    v.w = in[(size_t)(base + 3) << 4];
    int s = v.x + v.y + v.z + v.w;
    lds[t] = s;
    __syncthreads();
    for (int off = 1; off < 256; off <<= 1) {
        int u = (t >= off) ? lds[t - off] : 0;
        __syncthreads();
        lds[t] += u;
        __syncthreads();
    }
    int excl = lds[t] - s;
    if (t == 255) partials[b] = lds[255];
    int4 o;
    o.x = excl;
    o.y = excl + v.x;
    o.z = o.y + v.y;
    o.w = o.z + v.z;
    *(int4*)(outp + base) = o;
}

// ---- scan_down with inlined mid: every block scans the 98 raw partials in LDS ----
__global__ __launch_bounds__(256) void scan_down_f(int* __restrict__ eoff,
                                                   int* __restrict__ noff,
                                                   const int* __restrict__ partials) {
    __shared__ int lds[98];
    int b = blockIdx.x, t = threadIdx.x;
    if (t < 98) lds[t] = partials[t];
    __syncthreads();
    if (t < 2) {
        int lo = t * 49, hi = lo + 49;
        int run = 0;
        for (int i = lo; i < hi; ++i) { int x = lds[i]; lds[i] = run; run += x; }
    }
    __syncthreads();
    int* outp; int lb;
    if (b < 49) { outp = eoff; lb = b; }
    else        { outp = noff; lb = b - 49; }
    int base = lb * 1024 + t * 4;
    int p = lds[b];
    int4 v = *(const int4*)(outp + base);
    v.x += p; v.y += p; v.z += p; v.w += p;
    *(int4*)(outp + base) = v;
}

// ---- prep: atomic-free CSR scatter + streamed x->f16 + 3 weight transposes -------
#define NB_CSR  1563
#define NB_CONV 6250
#define NB_W1   128
#define NB_W2   512
#define NB_W3   512
__global__ __launch_bounds__(256) void prep_kernel(const int* __restrict__ nidx,
                                                   const int* __restrict__ eidx,
                                                   const unsigned short* __restrict__ rn,
                                                   const unsigned short* __restrict__ re,
                                                   const int* __restrict__ eoff,
                                                   const int* __restrict__ noff,
                                                   unsigned short* __restrict__ csre,
                                                   unsigned short* __restrict__ csrn,
                                                   const float* __restrict__ x,
                                                   unsigned short* __restrict__ xbf,
                                                   const float* __restrict__ W1, unsigned short* __restrict__ wt1,
                                                   const float* __restrict__ W2, unsigned short* __restrict__ wt2,
                                                   const float* __restrict__ W3, unsigned short* __restrict__ wt3) {
    int b = blockIdx.x, t = threadIdx.x;
    if (b < NB_CSR) {
        int i = b * 256 + t;
        if (i < N_INC) {
            int n = nidx[i], e = eidx[i];
            csre[eoff[e] + re[i]] = (unsigned short)n;
            csrn[noff[n] + rn[i]] = (unsigned short)e;
        }
    } else if (b < NB_CSR + NB_CONV) {
        int i = (b - NB_CSR) * 256 + t;
        float4 v = *(const float4*)(x + 4 * (size_t)i);
        ushort4 o;
        o.x = f2h(v.x); o.y = f2h(v.y); o.z = f2h(v.z); o.w = f2h(v.w);
        *(ushort4*)(xbf + 4 * (size_t)i) = o;
    } else if (b < NB_CSR + NB_CONV + NB_W1) {
        int i = (b - NB_CSR - NB_CONV) * 256 + t;
        int k = i >> 8, n = i & 255;
        wt1[n * 128 + k] = f2h(W1[i]);
    } else if (b < NB_CSR + NB_CONV + NB_W1 + NB_W2) {
        int i = (b - NB_CSR - NB_CONV - NB_W1) * 256 + t;
        int k = i >> 9, n = i & 511;
        wt2[n * 256 + k] = f2h(W2[i]);
    } else {
        int i = (b - NB_CSR - NB_CONV - NB_W1 - NB_W2) * 256 + t;
        int k = i >> 8, n = i & 255;
        wt3[n * 512 + k] = f2h(W3[i]);
    }
}

// ---------------- 128x128 MFMA GEMM (f16), BK=64 staging + XOR swizzle ------------
// Row-major A/Bt/C (R2 structure). 1D grid + bijective XCD chunking (m204):
// consecutive wg share the same A row-panel -> each XCD's L2 fetches A once.
template <bool EPI>
__global__ __launch_bounds__(256) void gemm128_kernel(const unsigned short* __restrict__ A,
                                                      const unsigned short* __restrict__ Bt,
                                                      const float* __restrict__ bias,
                                                      unsigned short* __restrict__ C,
                                                      int M, int K, int N) {
    __shared__ unsigned short smem[2 * 128 * 64];    // As | Bs, 32 KiB
    unsigned short* As = smem;
    unsigned short* Bs = smem + 128 * 64;
    int tid  = threadIdx.x;
    int wave = tid >> 6, lane = tid & 63;

    // XCD-chunked bijective remap of the 1D grid
    int nx  = N >> 7;
    int nwg = gridDim.x;
    int bid = blockIdx.x;
    int q = nwg >> 3, r = nwg & 7;
    int xcd = bid & 7, loc = bid >> 3;
    int wg = (xcd < r) ? (xcd * (q + 1) + loc) : (r * (q + 1) + (xcd - r) * q + loc);
    int n0 = (wg % nx) * 128, m0 = (wg / nx) * 128;

    int quad = lane >> 4, fr = lane & 15;
    int wr = wave >> 1, wc = wave & 1;
    int lrow8 = lane >> 3;                   // row within each 8-row staging group
    int lcol  = ((lane & 7) ^ lrow8) * 8;    // inverse-swizzled 16B slot (ushorts)

    const unsigned short* gsrc;
    unsigned short* ldst;
    if (wave < 2) { gsrc = A  + (size_t)(m0 + wave * 64) * K;       ldst = As + wave * 64 * 64; }
    else          { gsrc = Bt + (size_t)(n0 + (wave - 2) * 64) * K; ldst = Bs + (wave - 2) * 64 * 64; }

    f32x4 acc[4][4];
#pragma unroll
    for (int s = 0; s < 4; ++s)
#pragma unroll
        for (int c = 0; c < 4; ++c) acc[s][c] = (f32x4){0.f, 0.f, 0.f, 0.f};

    int swz = fr & 7;                        // == row&7 for all fragment rows
    for (int k0 = 0; k0 < K; k0 += 64) {
#pragma unroll
        for (int l = 0; l < 8; ++l) {
            const unsigned short* g = gsrc + (size_t)(l * 8 + lrow8) * K + k0 + lcol;
            load_lds16(g, ldst + l * 8 * 64);
        }
        __syncthreads();
#pragma unroll
        for (int kk = 0; kk < 2; ++kk) {
            int slot = (kk * 4 + quad) ^ swz;
            f16x8 af[4], bfr[4];
#pragma unroll
            for (int s = 0; s < 4; ++s)
                af[s] = *(const f16x8*)&As[(wr * 64 + s * 16 + fr) * 64 + slot * 8];
#pragma unroll
            for (int c = 0; c < 4; ++c)
                bfr[c] = *(const f16x8*)&Bs[(wc * 64 + c * 16 + fr) * 64 + slot * 8];
#pragma unroll
            for (int s = 0; s < 4; ++s)
#pragma unroll
                for (int c = 0; c < 4; ++c)
                    acc[s][c] = __builtin_amdgcn_mfma_f32_16x16x32_f16(af[s], bfr[c], acc[s][c], 0, 0, 0);
        }
        __syncthreads();
    }

    float bv[4];
#pragma unroll
    for (int c = 0; c < 4; ++c) bv[c] = EPI ? bias[n0 + wc * 64 + c * 16 + fr] : 0.f;
    // Cs aliases the staging LDS (dead after the loop's final barrier).
    unsigned short (*Cs)[136] = reinterpret_cast<unsigned short (*)[136]>(smem);
#pragma unroll
    for (int sp = 0; sp < 2; ++sp) {
#pragma unroll
        for (int sl = 0; sl < 2; ++sl) {
#pragma unroll
            for (int c = 0; c < 4; ++c)
#pragma unroll
                for (int r = 0; r < 4; ++r) {
                    float v = acc[sp * 2 + sl][c][r];
                    if (EPI) v = fmaxf(v + bv[c], 0.f);
                    Cs[sl * 32 + wr * 16 + quad * 4 + r][wc * 64 + c * 16 + fr] = f2h(v);
                }
        }
        __syncthreads();
#pragma unroll
        for (int i = 0; i < 4; ++i) {
            int rl  = i * 16 + (tid >> 4);                 // 0..63
            int col = (tid & 15) * 8;
            int gm  = m0 + ((rl & 31) >> 4) * 64 + (sp * 2 + (rl >> 5)) * 16 + (rl & 15);
            if (gm < M) {
                uint4 v = *(const uint4*)&Cs[rl][col];
                *(uint4*)&C[(size_t)gm * N + n0 + col] = v;
            }
        }
        __syncthreads();
    }
}

// ---- segment-mean gather (R2 structure, f16 accumulate, 2-deep batch pipeline) ---
// r5 diagnosis: latency/MLP-bound -- each batch serializes idx(~200cy) -> rows
// (~500-900cy) -> pk_add. 2-deep software pipeline with NAMED double buffers
// (vA/vB, all static indexing -- rule #20) issues batch k+1's idx+row loads before
// batch k's accumulate waits, doubling outstanding loads per wave. VGPR ~110 drops
// occupancy ~8->5 waves/SIMD but net outstanding bytes/CU rises and the idx->row
// chain is hidden. Accumulation order unchanged (batches in order) -> R8 numerics.
template <int C, bool BIAS>
__device__ __forceinline__ void seg_bodyN(const unsigned short* __restrict__ in,
                                          const int* __restrict__ offs,
                                          const int* __restrict__ degs_p,
                                          const unsigned short* __restrict__ csr_src,
                                          const float* __restrict__ bias,
                                          unsigned short* __restrict__ outp,
                                          int nseg) {
    constexpr int LPG = C / 8;       // lanes per segment group (32 for C=256, 16 for C=128)
    constexpr int SPW = 64 / LPG;    // segments per wave
    int wid  = (blockIdx.x * 256 + threadIdx.x) >> 6;
    int lane = threadIdx.x & 63;
    int grp = lane / LPG, lg = lane % LPG;
    int seg = SPW * wid + grp;
    if (SPW * wid >= nseg) return;
    bool segvalid = seg < nseg;
    int deg   = segvalid ? degs_p[(size_t)seg << 4] : 0;
    int start = segvalid ? offs[seg] : 0;
    float dinv = (deg > 0) ? 1.0f / (float)deg : 0.0f;
    int maxdeg = deg;
#pragma unroll
    for (int m = LPG; m < 64; m <<= 1) maxdeg = max(maxdeg, __shfl_xor(maxdeg, m, 64));
    const unsigned short* cs = csr_src + start;
    h16x2 hacc[4];
#pragma unroll
    for (int q = 0; q < 4; ++q) hacc[q] = (h16x2)0;
    size_t lbase = (size_t)lg * 8;
    int dc = (deg > 0) ? deg - 1 : 0;

    unsigned int vA[8][4], vB[8][4];

#define SEG_STAGE(jb, v)                                                          \
    if ((jb) < deg) {                                                             \
        int row_[8];                                                              \
        _Pragma("unroll")                                                         \
        for (int u = 0; u < 8; ++u) row_[u] = (int)cs[min((jb) + u, dc)];         \
        _Pragma("unroll")                                                         \
        for (int u = 0; u < 8; ++u) {                                             \
            int src_ = min(row_[u], nseg - 1);                                    \
            uint4 t_ = *(const uint4*)(in + (size_t)src_ * C + lbase);            \
            v[u][0] = t_.x; v[u][1] = t_.y; v[u][2] = t_.z; v[u][3] = t_.w;       \
        }                                                                         \
    }

#define SEG_ACCUM(jb, v)                                                          \
    if ((jb) < deg) {                                                             \
        if ((jb) + 8 <= deg) {                                                    \
            _Pragma("unroll")                                                     \
            for (int u = 0; u < 8; ++u)                                           \
                _Pragma("unroll")                                                 \
                for (int q = 0; q < 4; ++q)                                       \
                    hacc[q] += __builtin_bit_cast(h16x2, v[u][q]);                \
        } else {                                                                  \
            _Pragma("unroll")                                                     \
            for (int u = 0; u < 8; ++u) {                                         \
                unsigned int msk_ = ((jb) + u < deg) ? 0xffffffffu : 0u;          \
                _Pragma("unroll")                                                 \
                for (int q = 0; q < 4; ++q)                                       \
                    hacc[q] += __builtin_bit_cast(h16x2, v[u][q] & msk_);         \
            }                                                                     \
        }                                                                         \
    }

    SEG_STAGE(0, vA)
    for (int j = 0; j < maxdeg; j += 16) {
        SEG_STAGE(j + 8, vB)
        __asm__ __volatile__("" ::: "memory");   // keep vB batch in flight past vA wait
        SEG_ACCUM(j, vA)
        SEG_STAGE(j + 16, vA)
        __asm__ __volatile__("" ::: "memory");
        SEG_ACCUM(j + 8, vB)
    }
#undef SEG_STAGE
#undef SEG_ACCUM

    if (!segvalid) return;
    unsigned int o[4];
#pragma unroll
    for (int q = 0; q < 4; ++q) {
        float a = (float)hacc[q][0] * dinv;
        float b = (float)hacc[q][1] * dinv;
        if constexpr (BIAS) {
            a = fmaxf(a + bias[lbase + 2 * q], 0.f);
            b = fmaxf(b + bias[lbase + 2 * q + 1], 0.f);
        }
        o[q] = packh(a, b);
    }
    *(uint4*)(outp + (size_t)seg * C + lbase) = make_uint4(o[0], o[1], o[2], o[3]);
}

template <int C>
__global__ __launch_bounds__(256) void seg_edge_t(const unsigned short* __restrict__ xl,
                                                  const int* __restrict__ eoff,
                                                  const int* __restrict__ edeg_p,
                                                  const unsigned short* __restrict__ csr_src,
                                                  unsigned short* __restrict__ ef) {
    seg_bodyN<C, false>(xl, eoff, edeg_p, csr_src, nullptr, ef, N_EDGES);
}

template <int C, bool BIAS>
__global__ __launch_bounds__(256) void seg_node_t(const unsigned short* __restrict__ ef,
                                                  const int* __restrict__ noff,
                                                  const int* __restrict__ ndeg_p,
                                                  const unsigned short* __restrict__ csr_src,
                                                  const float* __restrict__ bias,
                                                  unsigned short* __restrict__ hout) {
    seg_bodyN<C, BIAS>(ef, noff, ndeg_p, csr_src, bias, hout, N_NODES);
}

// ---------------- fused mean pool + MLP head (one block per graph) ----------------
__global__ __launch_bounds__(256) void pool_head_kernel(const unsigned short* __restrict__ h,
                                                        const int* __restrict__ goff,
                                                        const float* __restrict__ Wl1,
                                                        const float* __restrict__ bl1,
                                                        const float* __restrict__ Wl2,
                                                        const float* __restrict__ bl2,
                                                        float* __restrict__ out) {
    __shared__ float xs[256];
    __shared__ float red[128];
    int g = blockIdx.x, t = threadIdx.x;
    int s = goff[g], cnt = goff[g + 1] - s;
    // 4 independent partial sums -> 4 row loads in flight (latency-bound loop)
    float a0 = 0.f, a1 = 0.f, a2 = 0.f, a3 = 0.f;
    int i = 0;
    for (; i + 4 <= cnt; i += 4) {
        unsigned short u0 = h[(size_t)(s + i + 0) * 256 + t];
        unsigned short u1 = h[(size_t)(s + i + 1) * 256 + t];
        unsigned short u2 = h[(size_t)(s + i + 2) * 256 + t];
        unsigned short u3 = h[(size_t)(s + i + 3) * 256 + t];
        a0 += h2f(u0); a1 += h2f(u1); a2 += h2f(u2); a3 += h2f(u3);
    }
    for (; i < cnt; ++i) a0 += h2f(h[(size_t)(s + i) * 256 + t]);
    float acc = (a0 + a1) + (a2 + a3);
    xs[t] = acc / (float)(cnt > 0 ? cnt : 1);
    __syncthreads();
    if (t < 128) {
        float s2 = 0.f;
        for (int f = 0; f < 256; ++f) s2 += xs[f] * Wl1[f * 128 + t];
        s2 = fmaxf(s2 + bl1[t], 0.f);
        red[t] = s2 * Wl2[t];
    }
    __syncthreads();
    for (int off = 64; off > 0; off >>= 1) {
        if (t < off) red[t] += red[t + off];
        __syncthreads();
    }
    if (t == 0) out[g] = red[0] + bl2[0];
}

extern "C" void kernel_launch(void* const* d_in, const int* in_sizes, int n_in,
                              void* d_out, int out_size, void* d_ws, size_t ws_size,
                              hipStream_t stream) {
    const float* x     = (const float*)d_in[0];
    const int* hei     = (const int*)d_in[1];
    const int* braw    = (const int*)d_in[2];
    const float* W1    = (const float*)d_in[3];
    const float* b1    = (const float*)d_in[4];
    const float* W2    = (const float*)d_in[5];
    const float* b2    = (const float*)d_in[6];
    const float* W3    = (const float*)d_in[7];
    const float* b3    = (const float*)d_in[8];
    const float* Wl1   = (const float*)d_in[9];
    const float* bl1   = (const float*)d_in[10];
    const float* Wl2   = (const float*)d_in[11];
    const float* bl2   = (const float*)d_in[12];
    float* out         = (float*)d_out;

    char* w = (char*)d_ws;
    size_t off = 0;
    auto alloc = [&](size_t bytes) { size_t p = off; off += (bytes + 255) & ~(size_t)255; return p; };
    size_t o_edegp = alloc((size_t)SEG_CAP * 16 * 4);
    size_t o_ndegp = alloc((size_t)SEG_CAP * 16 * 4);
    size_t zero_end = off;
    size_t o_eoff = alloc((size_t)SEG_CAP * 4);
    size_t o_noff = alloc((size_t)SEG_CAP * 4);
    size_t o_goff = alloc((size_t)1025 * 4);
    size_t o_part = alloc(128 * 4);
    size_t o_nidx = alloc((size_t)N_INC * 4);
    size_t o_eidx = alloc((size_t)N_INC * 4);
    size_t o_rn   = alloc((size_t)N_INC * 2);
    size_t o_re   = alloc((size_t)N_INC * 2);
    size_t o_csre = alloc((size_t)N_INC * 2 + 64);   // +slack for clamped tail reads
    size_t o_csrn = alloc((size_t)N_INC * 2 + 64);
    size_t o_wt1  = alloc((size_t)128 * 256 * 2);
    size_t o_wt2  = alloc((size_t)256 * 512 * 2);
    size_t o_wt3  = alloc((size_t)512 * 256 * 2);
    size_t o_xbf  = alloc((size_t)M_PAD * 128 * 2);
    size_t o_Y    = alloc((size_t)M_PAD * 256 * 2);
    size_t o_H1   = alloc((size_t)M_PAD * 256 * 2);
    size_t o_H2   = alloc((size_t)M_PAD * 512 * 2);
    size_t o_bufE = alloc((size_t)N_EDGES * 256 * 2);

    int* edeg_p = (int*)(w + o_edegp);
    int* ndeg_p = (int*)(w + o_ndegp);
    int* eoff = (int*)(w + o_eoff);
    int* noff = (int*)(w + o_noff);
    int* goff = (int*)(w + o_goff);
    int* part = (int*)(w + o_part);
    int* nidx = (int*)(w + o_nidx);
    int* eidx = (int*)(w + o_eidx);
    unsigned short* rn   = (unsigned short*)(w + o_rn);
    unsigned short* re   = (unsigned short*)(w + o_re);
    unsigned short* csre = (unsigned short*)(w + o_csre);
    unsigned short* csrn = (unsigned short*)(w + o_csrn);
    unsigned short* wt1  = (unsigned short*)(w + o_wt1);
    unsigned short* wt2  = (unsigned short*)(w + o_wt2);
    unsigned short* wt3  = (unsigned short*)(w + o_wt3);
    unsigned short* xbf  = (unsigned short*)(w + o_xbf);
    unsigned short* Y    = (unsigned short*)(w + o_Y);
    unsigned short* H1   = (unsigned short*)(w + o_H1);
    unsigned short* H2   = (unsigned short*)(w + o_H2);
    unsigned short* bufE = (unsigned short*)(w + o_bufE);

    hipMemsetAsync(w, 0, zero_end, stream);
    normhist_kernel<<<NB_INC, 256, 0, stream>>>(hei, nidx, eidx, rn, re, ndeg_p, edeg_p);
    scan_up_f<<<102, 256, 0, stream>>>(edeg_p, ndeg_p, hei, braw, eoff, noff, goff, part);
    scan_down_f<<<98, 256, 0, stream>>>(eoff, noff, part);
    prep_kernel<<<NB_CSR + NB_CONV + NB_W1 + NB_W2 + NB_W3, 256, 0, stream>>>(
        nidx, eidx, rn, re, eoff, noff, csre, csrn, x, xbf, W1, wt1, W2, wt2, W3, wt3);

    int segGrid2 = ((N_NODES + 1) / 2 * 64 + 255) / 256;   // SPW=2 (C=256)
    int segGrid4 = ((N_NODES + 3) / 4 * 64 + 255) / 256;   // SPW=4 (C=128)

    // ---- layer 1 (aggregate-first at 128)
    seg_edge_t<128><<<segGrid4, 256, 0, stream>>>(xbf, eoff, edeg_p, csre, bufE);
    seg_node_t<128, false><<<segGrid4, 256, 0, stream>>>(bufE, noff, ndeg_p, csrn, nullptr, Y);
    {
        dim3 grid((256 / 128) * (M_PAD / 128));
        gemm128_kernel<true><<<grid, 256, 0, stream>>>(Y, wt1, b1, H1, N_NODES, 128, 256);
    }
    // ---- layer 2 (aggregate-first at 256)
    seg_edge_t<256><<<segGrid2, 256, 0, stream>>>(H1, eoff, edeg_p, csre, bufE);
    seg_node_t<256, false><<<segGrid2, 256, 0, stream>>>(bufE, noff, ndeg_p, csrn, nullptr, Y);
    {
        dim3 grid((512 / 128) * (M_PAD / 128));
        gemm128_kernel<true><<<grid, 256, 0, stream>>>(Y, wt2, b2, H2, N_NODES, 256, 512);
    }
    // ---- layer 3 (gemm-first at 256)
    {
        dim3 grid((256 / 128) * (M_PAD / 128));
        gemm128_kernel<false><<<grid, 256, 0, stream>>>(H2, wt3, nullptr, Y, N_NODES, 512, 256);
    }
    seg_edge_t<256><<<segGrid2, 256, 0, stream>>>(Y, eoff, edeg_p, csre, bufE);
    seg_node_t<256, true><<<segGrid2, 256, 0, stream>>>(bufE, noff, ndeg_p, csrn, b3, H1);

    pool_head_kernel<<<N_GRAPHS, 256, 0, stream>>>(H1, goff, Wl1, bl1, Wl2, bl2, out);
}

// Round 10
// 378.024 us; speedup vs baseline: 1.0251x; 1.0251x over previous
//
#include <hip/hip_runtime.h>
#include <hip/hip_bf16.h>

#define N_NODES  50000
#define N_EDGES  50000
#define N_INC    400000
#define N_GRAPHS 1024
#define M_PAD    50048          // 391 * 128
#define SEG_CAP  50176          // 49 * 1024 (scan padding)

typedef _Float16 f16x8 __attribute__((ext_vector_type(8)));
typedef _Float16 h16x2 __attribute__((ext_vector_type(2)));
typedef float    f32x4 __attribute__((ext_vector_type(4)));

__device__ __forceinline__ unsigned short f2h(float f) {
    _Float16 h = (_Float16)f;                      // v_cvt_f16_f32 (RTE)
    return __builtin_bit_cast(unsigned short, h);
}
__device__ __forceinline__ float h2f(unsigned short u) {
    return (float)__builtin_bit_cast(_Float16, u);
}
__device__ __forceinline__ unsigned int packh(float a, float b) {
    return (unsigned int)f2h(a) | ((unsigned int)f2h(b) << 16);
}
__device__ __forceinline__ void load_lds16(const unsigned short* g, unsigned short* l) {
    __builtin_amdgcn_global_load_lds((const __attribute__((address_space(1))) void*)g,
                                     (__attribute__((address_space(3))) void*)l, 16, 0, 0);
}

// ---- normhist: incidence histogram only (padded counters, atomic returns = rank) --
#define NB_INC  1563
__global__ __launch_bounds__(256) void normhist_kernel(const int* __restrict__ hei,
                                                       int* __restrict__ nidx, int* __restrict__ eidx,
                                                       unsigned short* __restrict__ rn,
                                                       unsigned short* __restrict__ re,
                                                       int* __restrict__ ndeg_p, int* __restrict__ edeg_p) {
    __shared__ int s32;
    int t = threadIdx.x;
    if (t == 0) s32 = 0;
    __syncthreads();
    int probe = hei[4 * t + 1] | hei[4 * t + 3];   // int64 layout => odd words zero
    if (probe) s32 = 1;
    __syncthreads();
    int is32 = s32;
    int i = blockIdx.x * 256 + t;
    if (i < N_INC) {
        int n, e;
        if (is32) { n = hei[i];     e = hei[N_INC + i]; }
        else      { n = hei[2 * i]; e = hei[2 * N_INC + 2 * i]; }
        nidx[i] = n; eidx[i] = e;
        rn[i] = (unsigned short)atomicAdd(&ndeg_p[n << 4], 1);
        re[i] = (unsigned short)atomicAdd(&edeg_p[e << 4], 1);
    }
}

// ---- scan_up over padded degree arrays + goff via binary search on sorted batch
__global__ __launch_bounds__(256) void scan_up_f(const int* __restrict__ edeg_p,
                                                 const int* __restrict__ ndeg_p,
                                                 const int* __restrict__ hei,
                                                 const int* __restrict__ braw,
                                                 int* __restrict__ eoff, int* __restrict__ noff,
                                                 int* __restrict__ goff,
                                                 int* __restrict__ partials) {
    int b = blockIdx.x, t = threadIdx.x;
    if (b >= 98) {
        __shared__ int s32;
        if (t == 0) s32 = 0;
        __syncthreads();
        int probe = hei[4 * t + 1] | hei[4 * t + 3];
        if (probe) s32 = 1;
        __syncthreads();
        int is32 = s32;
        int g = (b - 98) * 256 + t;
        int lo = 0, hi = N_NODES;
        while (lo < hi) {
            int mid = (lo + hi) >> 1;
            int v = is32 ? braw[mid] : braw[2 * mid];
            if (v < g) lo = mid + 1; else hi = mid;
        }
        goff[g] = lo;
        if (g == 1023) goff[1024] = N_NODES;
        return;
    }
    __shared__ int lds[256];
    const int* in; int* outp; int lb;
    if (b < 49) { in = edeg_p; outp = eoff; lb = b; }
    else        { in = ndeg_p; outp = noff; lb = b - 49; }
    int base = lb * 1024 + t * 4;
    int4 v;
    v.x = in[(size_t)(base + 0) << 4];
    v.y = in[(size_t)(base + 1) << 4];
    v.z = in[(size_t)(base + 2) << 4];
    v.w = in[(size_t)(base + 3) << 4];
    int s = v.x + v.y + v.z + v.w;
    lds[t] = s;
    __syncthreads();
    for (int off = 1; off < 256; off <<= 1) {
        int u = (t >= off) ? lds[t - off] : 0;
        __syncthreads();
        lds[t] += u;
        __syncthreads();
    }
    int excl = lds[t] - s;
    if (t == 255) partials[b] = lds[255];
    int4 o;
    o.x = excl;
    o.y = excl + v.x;
    o.z = o.y + v.y;
    o.w = o.z + v.z;
    *(int4*)(outp + base) = o;
}

// ---- scan_down with inlined mid: every block scans the 98 raw partials in LDS ----
__global__ __launch_bounds__(256) void scan_down_f(int* __restrict__ eoff,
                                                   int* __restrict__ noff,
                                                   const int* __restrict__ partials) {
    __shared__ int lds[98];
    int b = blockIdx.x, t = threadIdx.x;
    if (t < 98) lds[t] = partials[t];
    __syncthreads();
    if (t < 2) {
        int lo = t * 49, hi = lo + 49;
        int run = 0;
        for (int i = lo; i < hi; ++i) { int x = lds[i]; lds[i] = run; run += x; }
    }
    __syncthreads();
    int* outp; int lb;
    if (b < 49) { outp = eoff; lb = b; }
    else        { outp = noff; lb = b - 49; }
    int base = lb * 1024 + t * 4;
    int p = lds[b];
    int4 v = *(const int4*)(outp + base);
    v.x += p; v.y += p; v.z += p; v.w += p;
    *(int4*)(outp + base) = v;
}

// ---- prep: atomic-free CSR scatter + streamed x->f16 + 3 weight transposes -------
#define NB_CSR  1563
#define NB_CONV 6250
#define NB_W1   128
#define NB_W2   512
#define NB_W3   512
__global__ __launch_bounds__(256) void prep_kernel(const int* __restrict__ nidx,
                                                   const int* __restrict__ eidx,
                                                   const unsigned short* __restrict__ rn,
                                                   const unsigned short* __restrict__ re,
                                                   const int* __restrict__ eoff,
                                                   const int* __restrict__ noff,
                                                   unsigned short* __restrict__ csre,
                                                   unsigned short* __restrict__ csrn,
                                                   const float* __restrict__ x,
                                                   unsigned short* __restrict__ xbf,
                                                   const float* __restrict__ W1, unsigned short* __restrict__ wt1,
                                                   const float* __restrict__ W2, unsigned short* __restrict__ wt2,
                                                   const float* __restrict__ W3, unsigned short* __restrict__ wt3) {
    int b = blockIdx.x, t = threadIdx.x;
    if (b < NB_CSR) {
        int i = b * 256 + t;
        if (i < N_INC) {
            int n = nidx[i], e = eidx[i];
            csre[eoff[e] + re[i]] = (unsigned short)n;
            csrn[noff[n] + rn[i]] = (unsigned short)e;
        }
    } else if (b < NB_CSR + NB_CONV) {
        int i = (b - NB_CSR) * 256 + t;
        float4 v = *(const float4*)(x + 4 * (size_t)i);
        ushort4 o;
        o.x = f2h(v.x); o.y = f2h(v.y); o.z = f2h(v.z); o.w = f2h(v.w);
        *(ushort4*)(xbf + 4 * (size_t)i) = o;
    } else if (b < NB_CSR + NB_CONV + NB_W1) {
        int i = (b - NB_CSR - NB_CONV) * 256 + t;
        int k = i >> 8, n = i & 255;
        wt1[n * 128 + k] = f2h(W1[i]);
    } else if (b < NB_CSR + NB_CONV + NB_W1 + NB_W2) {
        int i = (b - NB_CSR - NB_CONV - NB_W1) * 256 + t;
        int k = i >> 9, n = i & 511;
        wt2[n * 256 + k] = f2h(W2[i]);
    } else {
        int i = (b - NB_CSR - NB_CONV - NB_W1 - NB_W2) * 256 + t;
        int k = i >> 8, n = i & 255;
        wt3[n * 512 + k] = f2h(W3[i]);
    }
}

// ---------------- 128x128 MFMA GEMM (f16), BK=64 staging + XOR swizzle ------------
// Row-major A/Bt/C (R2 structure). 1D grid + bijective XCD chunking (m204):
// consecutive wg share the same A row-panel -> each XCD's L2 fetches A once.
template <bool EPI>
__global__ __launch_bounds__(256) void gemm128_kernel(const unsigned short* __restrict__ A,
                                                      const unsigned short* __restrict__ Bt,
                                                      const float* __restrict__ bias,
                                                      unsigned short* __restrict__ C,
                                                      int M, int K, int N) {
    __shared__ unsigned short smem[2 * 128 * 64];    // As | Bs, 32 KiB
    unsigned short* As = smem;
    unsigned short* Bs = smem + 128 * 64;
    int tid  = threadIdx.x;
    int wave = tid >> 6, lane = tid & 63;

    // XCD-chunked bijective remap of the 1D grid
    int nx  = N >> 7;
    int nwg = gridDim.x;
    int bid = blockIdx.x;
    int q = nwg >> 3, r = nwg & 7;
    int xcd = bid & 7, loc = bid >> 3;
    int wg = (xcd < r) ? (xcd * (q + 1) + loc) : (r * (q + 1) + (xcd - r) * q + loc);
    int n0 = (wg % nx) * 128, m0 = (wg / nx) * 128;

    int quad = lane >> 4, fr = lane & 15;
    int wr = wave >> 1, wc = wave & 1;
    int lrow8 = lane >> 3;                   // row within each 8-row staging group
    int lcol  = ((lane & 7) ^ lrow8) * 8;    // inverse-swizzled 16B slot (ushorts)

    const unsigned short* gsrc;
    unsigned short* ldst;
    if (wave < 2) { gsrc = A  + (size_t)(m0 + wave * 64) * K;       ldst = As + wave * 64 * 64; }
    else          { gsrc = Bt + (size_t)(n0 + (wave - 2) * 64) * K; ldst = Bs + (wave - 2) * 64 * 64; }

    f32x4 acc[4][4];
#pragma unroll
    for (int s = 0; s < 4; ++s)
#pragma unroll
        for (int c = 0; c < 4; ++c) acc[s][c] = (f32x4){0.f, 0.f, 0.f, 0.f};

    int swz = fr & 7;                        // == row&7 for all fragment rows
    for (int k0 = 0; k0 < K; k0 += 64) {
#pragma unroll
        for (int l = 0; l < 8; ++l) {
            const unsigned short* g = gsrc + (size_t)(l * 8 + lrow8) * K + k0 + lcol;
            load_lds16(g, ldst + l * 8 * 64);
        }
        __syncthreads();
#pragma unroll
        for (int kk = 0; kk < 2; ++kk) {
            int slot = (kk * 4 + quad) ^ swz;
            f16x8 af[4], bfr[4];
#pragma unroll
            for (int s = 0; s < 4; ++s)
                af[s] = *(const f16x8*)&As[(wr * 64 + s * 16 + fr) * 64 + slot * 8];
#pragma unroll
            for (int c = 0; c < 4; ++c)
                bfr[c] = *(const f16x8*)&Bs[(wc * 64 + c * 16 + fr) * 64 + slot * 8];
#pragma unroll
            for (int s = 0; s < 4; ++s)
#pragma unroll
                for (int c = 0; c < 4; ++c)
                    acc[s][c] = __builtin_amdgcn_mfma_f32_16x16x32_f16(af[s], bfr[c], acc[s][c], 0, 0, 0);
        }
        __syncthreads();
    }

    float bv[4];
#pragma unroll
    for (int c = 0; c < 4; ++c) bv[c] = EPI ? bias[n0 + wc * 64 + c * 16 + fr] : 0.f;
    // Cs aliases the staging LDS (dead after the loop's final barrier).
    unsigned short (*Cs)[136] = reinterpret_cast<unsigned short (*)[136]>(smem);
#pragma unroll
    for (int sp = 0; sp < 2; ++sp) {
#pragma unroll
        for (int sl = 0; sl < 2; ++sl) {
#pragma unroll
            for (int c = 0; c < 4; ++c)
#pragma unroll
                for (int r = 0; r < 4; ++r) {
                    float v = acc[sp * 2 + sl][c][r];
                    if (EPI) v = fmaxf(v + bv[c], 0.f);
                    Cs[sl * 32 + wr * 16 + quad * 4 + r][wc * 64 + c * 16 + fr] = f2h(v);
                }
        }
        __syncthreads();
#pragma unroll
        for (int i = 0; i < 4; ++i) {
            int rl  = i * 16 + (tid >> 4);                 // 0..63
            int col = (tid & 15) * 8;
            int gm  = m0 + ((rl & 31) >> 4) * 64 + (sp * 2 + (rl >> 5)) * 16 + (rl & 15);
            if (gm < M) {
                uint4 v = *(const uint4*)&Cs[rl][col];
                *(uint4*)&C[(size_t)gm * N + n0 + col] = v;
            }
        }
        __syncthreads();
    }
}

// ---- segment-mean gather (R8 structure + index-only 2-deep prefetch) -------------
// R9 lesson: full row double-buffering costs ~64 VGPR -> occupancy halves -> wash.
// This version prefetches ONLY the next batch's 8 csr indices (iA/iB, +16 VGPR,
// occupancy unchanged at 8 waves/SIMD): while batch k's row loads are in flight,
// batch k+1's indices load in their shadow, so rows(k+1) issue immediately after
// accum(k) -- removes the ~200-300cy idx stage from every batch after the first.
// Named buffers + static indexing (rule #20). Accumulation order identical to R8.
template <int C, bool BIAS>
__device__ __forceinline__ void seg_bodyN(const unsigned short* __restrict__ in,
                                          const int* __restrict__ offs,
                                          const int* __restrict__ degs_p,
                                          const unsigned short* __restrict__ csr_src,
                                          const float* __restrict__ bias,
                                          unsigned short* __restrict__ outp,
                                          int nseg) {
    constexpr int LPG = C / 8;       // lanes per segment group (32 for C=256, 16 for C=128)
    constexpr int SPW = 64 / LPG;    // segments per wave
    int wid  = (blockIdx.x * 256 + threadIdx.x) >> 6;
    int lane = threadIdx.x & 63;
    int grp = lane / LPG, lg = lane % LPG;
    int seg = SPW * wid + grp;
    if (SPW * wid >= nseg) return;
    bool segvalid = seg < nseg;
    int deg   = segvalid ? degs_p[(size_t)seg << 4] : 0;
    int start = segvalid ? offs[seg] : 0;
    float dinv = (deg > 0) ? 1.0f / (float)deg : 0.0f;
    int maxdeg = deg;
#pragma unroll
    for (int m = LPG; m < 64; m <<= 1) maxdeg = max(maxdeg, __shfl_xor(maxdeg, m, 64));
    const unsigned short* cs = csr_src + start;
    h16x2 hacc[4];
#pragma unroll
    for (int q = 0; q < 4; ++q) hacc[q] = (h16x2)0;
    size_t lbase = (size_t)lg * 8;
    int dc = (deg > 0) ? deg - 1 : 0;

    int iA[8], iB[8];

#define SEG_LOADIDX(jb, arr)                                                      \
    if ((jb) < deg) {                                                             \
        _Pragma("unroll")                                                         \
        for (int u = 0; u < 8; ++u) arr[u] = (int)cs[min((jb) + u, dc)];          \
    }

#define SEG_ROWS_ACCUM(jb, arr)                                                   \
    if ((jb) < deg) {                                                             \
        unsigned int v_[8][4];                                                    \
        _Pragma("unroll")                                                         \
        for (int u = 0; u < 8; ++u) {                                             \
            int src_ = min(arr[u], nseg - 1);                                     \
            uint4 t_ = *(const uint4*)(in + (size_t)src_ * C + lbase);            \
            v_[u][0] = t_.x; v_[u][1] = t_.y; v_[u][2] = t_.z; v_[u][3] = t_.w;   \
        }                                                                         \
        __asm__ __volatile__("" ::: "memory");                                    \
        if ((jb) + 8 <= deg) {                                                    \
            _Pragma("unroll")                                                     \
            for (int u = 0; u < 8; ++u)                                           \
                _Pragma("unroll")                                                 \
                for (int q = 0; q < 4; ++q)                                       \
                    hacc[q] += __builtin_bit_cast(h16x2, v_[u][q]);               \
        } else {                                                                  \
            _Pragma("unroll")                                                     \
            for (int u = 0; u < 8; ++u) {                                         \
                unsigned int msk_ = ((jb) + u < deg) ? 0xffffffffu : 0u;          \
                _Pragma("unroll")                                                 \
                for (int q = 0; q < 4; ++q)                                       \
                    hacc[q] += __builtin_bit_cast(h16x2, v_[u][q] & msk_);        \
            }                                                                     \
        }                                                                         \
    }

    SEG_LOADIDX(0, iA)
    for (int j = 0; j < maxdeg; j += 16) {
        SEG_LOADIDX(j + 8, iB)       // prefetch next batch's indices
        SEG_ROWS_ACCUM(j, iA)
        SEG_LOADIDX(j + 16, iA)
        SEG_ROWS_ACCUM(j + 8, iB)
    }
#undef SEG_LOADIDX
#undef SEG_ROWS_ACCUM

    if (!segvalid) return;
    unsigned int o[4];
#pragma unroll
    for (int q = 0; q < 4; ++q) {
        float a = (float)hacc[q][0] * dinv;
        float b = (float)hacc[q][1] * dinv;
        if constexpr (BIAS) {
            a = fmaxf(a + bias[lbase + 2 * q], 0.f);
            b = fmaxf(b + bias[lbase + 2 * q + 1], 0.f);
        }
        o[q] = packh(a, b);
    }
    *(uint4*)(outp + (size_t)seg * C + lbase) = make_uint4(o[0], o[1], o[2], o[3]);
}

template <int C>
__global__ __launch_bounds__(256) void seg_edge_t(const unsigned short* __restrict__ xl,
                                                  const int* __restrict__ eoff,
                                                  const int* __restrict__ edeg_p,
                                                  const unsigned short* __restrict__ csr_src,
                                                  unsigned short* __restrict__ ef) {
    seg_bodyN<C, false>(xl, eoff, edeg_p, csr_src, nullptr, ef, N_EDGES);
}

template <int C, bool BIAS>
__global__ __launch_bounds__(256) void seg_node_t(const unsigned short* __restrict__ ef,
                                                  const int* __restrict__ noff,
                                                  const int* __restrict__ ndeg_p,
                                                  const unsigned short* __restrict__ csr_src,
                                                  const float* __restrict__ bias,
                                                  unsigned short* __restrict__ hout) {
    seg_bodyN<C, BIAS>(ef, noff, ndeg_p, csr_src, bias, hout, N_NODES);
}

// ---------------- fused mean pool + MLP head (one block per graph) ----------------
__global__ __launch_bounds__(256) void pool_head_kernel(const unsigned short* __restrict__ h,
                                                        const int* __restrict__ goff,
                                                        const float* __restrict__ Wl1,
                                                        const float* __restrict__ bl1,
                                                        const float* __restrict__ Wl2,
                                                        const float* __restrict__ bl2,
                                                        float* __restrict__ out) {
    __shared__ float xs[256];
    __shared__ float red[128];
    int g = blockIdx.x, t = threadIdx.x;
    int s = goff[g], cnt = goff[g + 1] - s;
    // 4 independent partial sums -> 4 row loads in flight (latency-bound loop)
    float a0 = 0.f, a1 = 0.f, a2 = 0.f, a3 = 0.f;
    int i = 0;
    for (; i + 4 <= cnt; i += 4) {
        unsigned short u0 = h[(size_t)(s + i + 0) * 256 + t];
        unsigned short u1 = h[(size_t)(s + i + 1) * 256 + t];
        unsigned short u2 = h[(size_t)(s + i + 2) * 256 + t];
        unsigned short u3 = h[(size_t)(s + i + 3) * 256 + t];
        a0 += h2f(u0); a1 += h2f(u1); a2 += h2f(u2); a3 += h2f(u3);
    }
    for (; i < cnt; ++i) a0 += h2f(h[(size_t)(s + i) * 256 + t]);
    float acc = (a0 + a1) + (a2 + a3);
    xs[t] = acc / (float)(cnt > 0 ? cnt : 1);
    __syncthreads();
    if (t < 128) {
        float s2 = 0.f;
        for (int f = 0; f < 256; ++f) s2 += xs[f] * Wl1[f * 128 + t];
        s2 = fmaxf(s2 + bl1[t], 0.f);
        red[t] = s2 * Wl2[t];
    }
    __syncthreads();
    for (int off = 64; off > 0; off >>= 1) {
        if (t < off) red[t] += red[t + off];
        __syncthreads();
    }
    if (t == 0) out[g] = red[0] + bl2[0];
}

extern "C" void kernel_launch(void* const* d_in, const int* in_sizes, int n_in,
                              void* d_out, int out_size, void* d_ws, size_t ws_size,
                              hipStream_t stream) {
    const float* x     = (const float*)d_in[0];
    const int* hei     = (const int*)d_in[1];
    const int* braw    = (const int*)d_in[2];
    const float* W1    = (const float*)d_in[3];
    const float* b1    = (const float*)d_in[4];
    const float* W2    = (const float*)d_in[5];
    const float* b2    = (const float*)d_in[6];
    const float* W3    = (const float*)d_in[7];
    const float* b3    = (const float*)d_in[8];
    const float* Wl1   = (const float*)d_in[9];
    const float* bl1   = (const float*)d_in[10];
    const float* Wl2   = (const float*)d_in[11];
    const float* bl2   = (const float*)d_in[12];
    float* out         = (float*)d_out;

    char* w = (char*)d_ws;
    size_t off = 0;
    auto alloc = [&](size_t bytes) { size_t p = off; off += (bytes + 255) & ~(size_t)255; return p; };
    size_t o_edegp = alloc((size_t)SEG_CAP * 16 * 4);
    size_t o_ndegp = alloc((size_t)SEG_CAP * 16 * 4);
    size_t zero_end = off;
    size_t o_eoff = alloc((size_t)SEG_CAP * 4);
    size_t o_noff = alloc((size_t)SEG_CAP * 4);
    size_t o_goff = alloc((size_t)1025 * 4);
    size_t o_part = alloc(128 * 4);
    size_t o_nidx = alloc((size_t)N_INC * 4);
    size_t o_eidx = alloc((size_t)N_INC * 4);
    size_t o_rn   = alloc((size_t)N_INC * 2);
    size_t o_re   = alloc((size_t)N_INC * 2);
    size_t o_csre = alloc((size_t)N_INC * 2 + 64);   // +slack for clamped tail reads
    size_t o_csrn = alloc((size_t)N_INC * 2 + 64);
    size_t o_wt1  = alloc((size_t)128 * 256 * 2);
    size_t o_wt2  = alloc((size_t)256 * 512 * 2);
    size_t o_wt3  = alloc((size_t)512 * 256 * 2);
    size_t o_xbf  = alloc((size_t)M_PAD * 128 * 2);
    size_t o_Y    = alloc((size_t)M_PAD * 256 * 2);
    size_t o_H1   = alloc((size_t)M_PAD * 256 * 2);
    size_t o_H2   = alloc((size_t)M_PAD * 512 * 2);
    size_t o_bufE = alloc((size_t)N_EDGES * 256 * 2);

    int* edeg_p = (int*)(w + o_edegp);
    int* ndeg_p = (int*)(w + o_ndegp);
    int* eoff = (int*)(w + o_eoff);
    int* noff = (int*)(w + o_noff);
    int* goff = (int*)(w + o_goff);
    int* part = (int*)(w + o_part);
    int* nidx = (int*)(w + o_nidx);
    int* eidx = (int*)(w + o_eidx);
    unsigned short* rn   = (unsigned short*)(w + o_rn);
    unsigned short* re   = (unsigned short*)(w + o_re);
    unsigned short* csre = (unsigned short*)(w + o_csre);
    unsigned short* csrn = (unsigned short*)(w + o_csrn);
    unsigned short* wt1  = (unsigned short*)(w + o_wt1);
    unsigned short* wt2  = (unsigned short*)(w + o_wt2);
    unsigned short* wt3  = (unsigned short*)(w + o_wt3);
    unsigned short* xbf  = (unsigned short*)(w + o_xbf);
    unsigned short* Y    = (unsigned short*)(w + o_Y);
    unsigned short* H1   = (unsigned short*)(w + o_H1);
    unsigned short* H2   = (unsigned short*)(w + o_H2);
    unsigned short* bufE = (unsigned short*)(w + o_bufE);

    hipMemsetAsync(w, 0, zero_end, stream);
    normhist_kernel<<<NB_INC, 256, 0, stream>>>(hei, nidx, eidx, rn, re, ndeg_p, edeg_p);
    scan_up_f<<<102, 256, 0, stream>>>(edeg_p, ndeg_p, hei, braw, eoff, noff, goff, part);
    scan_down_f<<<98, 256, 0, stream>>>(eoff, noff, part);
    prep_kernel<<<NB_CSR + NB_CONV + NB_W1 + NB_W2 + NB_W3, 256, 0, stream>>>(
        nidx, eidx, rn, re, eoff, noff, csre, csrn, x, xbf, W1, wt1, W2, wt2, W3, wt3);

    int segGrid2 = ((N_NODES + 1) / 2 * 64 + 255) / 256;   // SPW=2 (C=256)
    int segGrid4 = ((N_NODES + 3) / 4 * 64 + 255) / 256;   // SPW=4 (C=128)

    // ---- layer 1 (aggregate-first at 128)
    seg_edge_t<128><<<segGrid4, 256, 0, stream>>>(xbf, eoff, edeg_p, csre, bufE);
    seg_node_t<128, false><<<segGrid4, 256, 0, stream>>>(bufE, noff, ndeg_p, csrn, nullptr, Y);
    {
        dim3 grid((256 / 128) * (M_PAD / 128));
        gemm128_kernel<true><<<grid, 256, 0, stream>>>(Y, wt1, b1, H1, N_NODES, 128, 256);
    }
    // ---- layer 2 (aggregate-first at 256)
    seg_edge_t<256><<<segGrid2, 256, 0, stream>>>(H1, eoff, edeg_p, csre, bufE);
    seg_node_t<256, false><<<segGrid2, 256, 0, stream>>>(bufE, noff, ndeg_p, csrn, nullptr, Y);
    {
        dim3 grid((512 / 128) * (M_PAD / 128));
        gemm128_kernel<true><<<grid, 256, 0, stream>>>(Y, wt2, b2, H2, N_NODES, 256, 512);
    }
    // ---- layer 3 (gemm-first at 256)
    {
        dim3 grid((256 / 128) * (M_PAD / 128));
        gemm128_kernel<false><<<grid, 256, 0, stream>>>(H2, wt3, nullptr, Y, N_NODES, 512, 256);
    }
    seg_edge_t<256><<<segGrid2, 256, 0, stream>>>(Y, eoff, edeg_p, csre, bufE);
    seg_node_t<256, true><<<segGrid2, 256, 0, stream>>>(bufE, noff, ndeg_p, csrn, b3, H1);

    pool_head_kernel<<<N_GRAPHS, 256, 0, stream>>>(H1, goff, Wl1, bl1, Wl2, bl2, out);
}